// Round 10
// baseline (1723.014 us; speedup 1.0000x reference)
//
#include <hip/hip_runtime.h>
#include <hip/hip_bf16.h>
#include <math.h>

// ---------------- static config ----------------
// B=4, H=W=256, TIN=10, F=4, P=8, CIN=12, E=768, NB=8, BS=96,
// HP=WP=32, MID=3072, DEPTH=4, LAM=0.01, WF=17, TOK=4096, POS=B*32*17=2176
// Spectral layout: X[((b*17+kw)*32 + h)*768 + c]   (h-rows contiguous per kw)
// R12: gemm128d (128-row tile, 8 waves, counted vmcnt) conv/head1.
// R15/R16: idft_w_mfma. R17: spec_fused 12 waves; fc2_fused 64x64 3 blk/CU.
// R18: conv/head1 -> gemm128d<64>; cvt_transpose8 batched.
// R19: fc1_deep -- 128x192, 8 waves, BK=64, THREE buffers (120KB, 1 blk/CU),
//   ONE barrier/tile, 2-tile-deep counted vmcnt(5), stage split across the
//   two ks compute phases (3 loads after ks0 reads, 2 after ks1). Buffer
//   lifecycle: buf (t+2)%3 last read in iter t-1; written after iter-t's
//   loop-top barrier -> single barrier orders both hazards.

typedef __attribute__((ext_vector_type(8))) _Float16 half8;
typedef __attribute__((ext_vector_type(4))) _Float16 half4v;
typedef __attribute__((ext_vector_type(4))) float float4v;

__device__ __forceinline__ float gelu_f(float v) {
    return 0.5f * v * (1.0f + erff(v * 0.70710678118654752f));
}
__device__ __forceinline__ float shrink_f(float v) {
    return (v > 0.01f) ? (v - 0.01f) : ((v < -0.01f) ? (v + 0.01f) : 0.0f);
}

#define STEP32 0.19634954084936207f  // 2*pi/32

// async 16B global->LDS (lds dest wave-uniform; HW adds lane*16)
__device__ __forceinline__ void async16(const void* g, void* l) {
    __builtin_amdgcn_global_load_lds(
        (const __attribute__((address_space(1))) unsigned int*)g,
        (__attribute__((address_space(3))) unsigned int*)l, 16, 0, 0);
}

// ---------------- gather patches into A_h [4096][768] f16 ----------------
__global__ __launch_bounds__(256) void gather_patch(const float* __restrict__ x,
        const float* __restrict__ grd, _Float16* __restrict__ A)
{
    int idx = blockIdx.x * 256 + threadIdx.x;
    int j   = idx % 768;
    int tok = idx / 768;
    int c = j >> 6, p = (j >> 3) & 7, q = j & 7;
    int wp = tok & 31, hp = (tok >> 5) & 31, b = tok >> 10;
    int hh = hp * 8 + p, ww = wp * 8 + q;
    float v;
    if (c < 10) v = x[((b * 256 + hh) * 256 + ww) * 10 + c];
    else        v = grd[((b * 256 + hh) * 256 + ww) * 2 + (c - 10)];
    A[idx] = (_Float16)v;
}

// ---------------- forward DFT along W (f16 in -> 17 complex f16), scale 1/32 ----------------
__global__ __launch_bounds__(256) void dft_fwd_w(const _Float16* __restrict__ th,
        _Float16* __restrict__ Xr, _Float16* __restrict__ Xi)
{
    __shared__ float2 lut[32];
    int bh = blockIdx.x;            // b*32 + h
    int tid = threadIdx.x;
    if (tid < 32) { float a = tid * STEP32; lut[tid] = make_float2(cosf(a), sinf(a)); }
    __syncthreads();
    int b = bh >> 5, h = bh & 31;
    int c = blockIdx.y * 256 + tid;
    float v[32];
    #pragma unroll
    for (int w = 0; w < 32; ++w) v[w] = (float)th[(bh * 32 + w) * 768 + c];
    for (int kw = 0; kw <= 16; ++kw) {
        float ar = 0.f, ai = 0.f;
        #pragma unroll
        for (int w = 0; w < 32; ++w) {
            float2 cs = lut[(kw * w) & 31];
            ar += v[w] * cs.x;
            ai -= v[w] * cs.y;
        }
        size_t g = ((size_t)(b * 17 + kw) * 32 + h) * 768 + c;
        Xr[g] = (_Float16)(ar * 0.03125f);
        Xi[g] = (_Float16)(ai * 0.03125f);
    }
}

// ---------------- R15: MFMA inverse W-DFT + f16 residual ----------------
__global__ __launch_bounds__(256) void idft_w_mfma(const _Float16* __restrict__ Yr,
        const _Float16* __restrict__ Yi, _Float16* __restrict__ th)
{
    __shared__ alignas(16) _Float16 Yt[192 * 40];   // [c_local][slot] pad-40, 15 KB
    __shared__ alignas(16) _Float16 El[32 * 40];    // [w][slot] pad-40, 2.5 KB

    const int tid  = threadIdx.x;
    const int wave = tid >> 6;          // 0..3
    const int lane = tid & 63;
    const int lr   = lane & 15;
    const int quad = lane >> 4;

    const int bh = blockIdx.x;
    const int b  = bh >> 5, h = bh & 31;
    const int c0 = blockIdx.y * 192;

    // E' twiddles (f16, factors folded)
    for (int i = tid; i < 1024; i += 256) {
        int w = i >> 5, s = i & 31;
        float val;
        if (s <= 16) {
            float g = (s == 0 || s == 16) ? 1.f : 2.f;
            val = g * cosf(((w * s) & 31) * STEP32) * 0.03125f;
        } else {
            int k = s - 16;
            val = -2.f * sinf(((w * k) & 31) * STEP32) * 0.03125f;
        }
        El[w * 40 + s] = (_Float16)val;
    }

    // stage Y' -> Yt[c][slot]: coalesced half8 loads; transpose scalar writes
    // with e^(cg&7) perm (spreads the 32-way same-bank write pattern to 8-way).
    #pragma unroll
    for (int i = 0; i < 3; ++i) {
        int u    = tid + i * 256;
        int slot = u / 24;
        int cg   = u % 24;
        const _Float16* src;
        if (slot < 17) src = Yr + ((size_t)(b * 17 + slot) * 32 + h) * 768;
        else           src = Yi + ((size_t)(b * 17 + (slot - 16)) * 32 + h) * 768;
        half8 v = *(const half8*)(src + c0 + cg * 8);
        #pragma unroll
        for (int e = 0; e < 8; ++e) {
            int el = e ^ (cg & 7);
            Yt[(cg * 8 + el) * 40 + slot] = v[el];
        }
    }
    __syncthreads();

    // MFMA: acc[m][n], m = w-half (0..1), n = c-frag (0..2)
    half8 af[2], bf[3];
    #pragma unroll
    for (int m = 0; m < 2; ++m)
        af[m] = *(const half8*)&El[(m * 16 + lr) * 40 + quad * 8];
    #pragma unroll
    for (int n = 0; n < 3; ++n)
        bf[n] = *(const half8*)&Yt[(wave * 48 + n * 16 + lr) * 40 + quad * 8];
    float4v acc[2][3];
    #pragma unroll
    for (int m = 0; m < 2; ++m)
        #pragma unroll
        for (int n = 0; n < 3; ++n) {
            float4v z = {0.f, 0.f, 0.f, 0.f};
            acc[m][n] = __builtin_amdgcn_mfma_f32_16x16x32_f16(af[m], bf[n], z, 0, 0, 0);
        }

    // residual RMW (same pattern as old dft_inv_w)
    #pragma unroll
    for (int m = 0; m < 2; ++m)
        #pragma unroll
        for (int n = 0; n < 3; ++n) {
            int c = c0 + wave * 48 + n * 16 + lr;
            #pragma unroll
            for (int r = 0; r < 4; ++r) {
                int w = m * 16 + quad * 4 + r;
                size_t gi = (size_t)(bh * 32 + w) * 768 + c;
                th[gi] = (_Float16)(acc[m][n][r] + (float)th[gi]);
            }
        }
}

// ---------------- spectral weight prep: [i][o] fp32 -> [o][i] f16, 128 matrices ----------------
__global__ __launch_bounds__(256) void prep_specw(const float* __restrict__ w1,
        const float* __restrict__ w2, _Float16* __restrict__ out)
{
    __shared__ float tile[96][97];
    int mid = blockIdx.x;
    int n  = mid & 7;
    int ri = (mid >> 3) & 1;
    int l  = (mid >> 4) & 1;
    int d  = mid >> 5;
    const float* src = (l ? w2 : w1) + ((size_t)(d * 2 + ri) * 8 + n) * 9216;
    for (int idx = threadIdx.x; idx < 9216; idx += 256)
        tile[idx / 96][idx % 96] = src[idx];
    __syncthreads();
    _Float16* dst = out + (size_t)mid * 9216;
    for (int idx = threadIdx.x; idx < 9216; idx += 256)
        dst[idx] = (_Float16)tile[idx % 96][idx / 96];   // dst[o][i] = src[i][o]
}

// ---------------- fused spectral: H-DFT -> spec1(gelu) -> spec2(shrink) -> H-IDFT ----------------
// IN-PLACE on X ([b,kw,h,c] layout). grid (68 = b*17+kw, 8 = n).
// R17: 768 thr = 12 waves; wave = (wr = wave/6 kh-half, wo = wave%6 frag idx).
__global__ __launch_bounds__(768) void spec_fused(
        _Float16* __restrict__ Xr, _Float16* __restrict__ Xi,
        const _Float16* __restrict__ W1r, const _Float16* __restrict__ W1i,
        const _Float16* __restrict__ W2r, const _Float16* __restrict__ W2i,
        const float* __restrict__ b1r, const float* __restrict__ b1i,
        const float* __restrict__ b2r, const float* __restrict__ b2i)
{
    __shared__ alignas(16) _Float16 Ec[1024], Es[1024];       // [m][k] twiddle 32x32
    __shared__ alignas(16) _Float16 XTr[3840], XTi[3840];     // [c][h] pad40; stage C: [o][kh]
    __shared__ alignas(16) _Float16 Zr[3328], Zi[3328];       // [kh][c] pad104; stage D out [h][c]
    __shared__ alignas(16) _Float16 Sr[3328], Si[3328];       // [kh][o] pad104

    const int bk = blockIdx.x;       // b*17 + kw
    const int n  = blockIdx.y;
    const int tid = threadIdx.x;
    const int wave = tid >> 6, lane = tid & 63;
    const int wr = wave / 6;         // kh/h half (0..1)
    const int wo = wave % 6;         // fragment index (0..5)
    const int lr = lane & 15, quad = lane >> 4;
    const size_t base = (size_t)bk * 24576 + n * 96;    // + h*768 + c

    for (int i = tid; i < 1024; i += 768) {
        int kh = i >> 5, h = i & 31;
        float a = ((kh * h) & 31) * STEP32;
        Ec[i] = (_Float16)cosf(a);
        Es[i] = (_Float16)sinf(a);
    }
    // vector load -> LDS transpose [c][h]
    for (int i = tid; i < 384; i += 768) {
        int h = i / 12, cc = (i % 12) * 8;
        half8 vr = *(const half8*)(Xr + base + (size_t)h * 768 + cc);
        half8 vi = *(const half8*)(Xi + base + (size_t)h * 768 + cc);
        #pragma unroll
        for (int e = 0; e < 8; ++e) {
            XTr[(cc + e) * 40 + h] = vr[e];
            XTi[(cc + e) * 40 + h] = vi[e];
        }
    }
    __syncthreads();

    const _Float16* w1r = W1r + (size_t)n * 9216;
    const _Float16* w1i = W1i + (size_t)n * 9216;
    const _Float16* w2r = W2r + (size_t)n * 9216;
    const _Float16* w2i = W2i + (size_t)n * 9216;

    half8 eC = *(const half8*)&Ec[(wr * 16 + lr) * 32 + quad * 8];
    half8 eS = *(const half8*)&Es[(wr * 16 + lr) * 32 + quad * 8];
    half8 eSn = -eS;

    // stage A: Z[kh][c] = DFT_h(X) -- wave handles c-tile wo
    {
        int c = wo * 16 + lr;
        float4v zr = {0,0,0,0}, zi = {0,0,0,0};
        half8 xr = *(const half8*)&XTr[c * 40 + quad * 8];
        half8 xi = *(const half8*)&XTi[c * 40 + quad * 8];
        zr = __builtin_amdgcn_mfma_f32_16x16x32_f16(eC,  xr, zr, 0, 0, 0);
        zr = __builtin_amdgcn_mfma_f32_16x16x32_f16(eS,  xi, zr, 0, 0, 0);
        zi = __builtin_amdgcn_mfma_f32_16x16x32_f16(eC,  xi, zi, 0, 0, 0);
        zi = __builtin_amdgcn_mfma_f32_16x16x32_f16(eSn, xr, zi, 0, 0, 0);
        #pragma unroll
        for (int r = 0; r < 4; ++r) {
            int kh = wr * 16 + quad * 4 + r;
            Zr[kh * 104 + c] = (_Float16)zr[r];
            Zi[kh * 104 + c] = (_Float16)zi[r];
        }
    }
    __syncthreads();

    // stage B: S = gelu(Z @ W1 + b1) -- wave handles o-tile wo
    {
        int o = wo * 16 + lr;
        float4v sr = {0,0,0,0}, si = {0,0,0,0};
        #pragma unroll
        for (int kc = 0; kc < 3; ++kc) {
            half8 ar = *(const half8*)&Zr[(wr * 16 + lr) * 104 + kc * 32 + quad * 8];
            half8 ai = *(const half8*)&Zi[(wr * 16 + lr) * 104 + kc * 32 + quad * 8];
            half8 ain = -ai;
            half8 br = *(const half8*)&w1r[o * 96 + kc * 32 + quad * 8];
            half8 bi = *(const half8*)&w1i[o * 96 + kc * 32 + quad * 8];
            sr = __builtin_amdgcn_mfma_f32_16x16x32_f16(ar,  br, sr, 0, 0, 0);
            sr = __builtin_amdgcn_mfma_f32_16x16x32_f16(ain, bi, sr, 0, 0, 0);
            si = __builtin_amdgcn_mfma_f32_16x16x32_f16(ai,  br, si, 0, 0, 0);
            si = __builtin_amdgcn_mfma_f32_16x16x32_f16(ar,  bi, si, 0, 0, 0);
        }
        float br = b1r[n * 96 + o], bi = b1i[n * 96 + o];
        #pragma unroll
        for (int r = 0; r < 4; ++r) {
            int kh = wr * 16 + quad * 4 + r;
            Sr[kh * 104 + o] = (_Float16)gelu_f(sr[r] + br);
            Si[kh * 104 + o] = (_Float16)gelu_f(si[r] + bi);
        }
    }
    __syncthreads();

    // stage C: T = shrink(S @ W2 + b2) -> transposed T2T[o][kh] (alias XT)
    {
        int o = wo * 16 + lr;
        float4v tr = {0,0,0,0}, ti = {0,0,0,0};
        #pragma unroll
        for (int kc = 0; kc < 3; ++kc) {
            half8 ar = *(const half8*)&Sr[(wr * 16 + lr) * 104 + kc * 32 + quad * 8];
            half8 ai = *(const half8*)&Si[(wr * 16 + lr) * 104 + kc * 32 + quad * 8];
            half8 ain = -ai;
            half8 br = *(const half8*)&w2r[o * 96 + kc * 32 + quad * 8];
            half8 bi = *(const half8*)&w2i[o * 96 + kc * 32 + quad * 8];
            tr = __builtin_amdgcn_mfma_f32_16x16x32_f16(ar,  br, tr, 0, 0, 0);
            tr = __builtin_amdgcn_mfma_f32_16x16x32_f16(ain, bi, tr, 0, 0, 0);
            ti = __builtin_amdgcn_mfma_f32_16x16x32_f16(ai,  br, ti, 0, 0, 0);
            ti = __builtin_amdgcn_mfma_f32_16x16x32_f16(ar,  bi, ti, 0, 0, 0);
        }
        float br = b2r[n * 96 + o], bi = b2i[n * 96 + o];
        #pragma unroll
        for (int r = 0; r < 4; ++r) {
            int kh = wr * 16 + quad * 4 + r;
            XTr[o * 40 + kh] = (_Float16)shrink_f(tr[r] + br);
            XTi[o * 40 + kh] = (_Float16)shrink_f(ti[r] + bi);
        }
    }
    __syncthreads();

    // stage D: Y[h][c] = IDFT_h(T2) -> Zr/Zi as [h][c] pad104
    {
        int c = wo * 16 + lr;
        float4v yr = {0,0,0,0}, yi = {0,0,0,0};
        half8 t2r = *(const half8*)&XTr[c * 40 + quad * 8];
        half8 t2i = *(const half8*)&XTi[c * 40 + quad * 8];
        yr = __builtin_amdgcn_mfma_f32_16x16x32_f16(eC,  t2r, yr, 0, 0, 0);
        yr = __builtin_amdgcn_mfma_f32_16x16x32_f16(eSn, t2i, yr, 0, 0, 0);
        yi = __builtin_amdgcn_mfma_f32_16x16x32_f16(eC,  t2i, yi, 0, 0, 0);
        yi = __builtin_amdgcn_mfma_f32_16x16x32_f16(eS,  t2r, yi, 0, 0, 0);
        #pragma unroll
        for (int r = 0; r < 4; ++r) {
            int h = wr * 16 + quad * 4 + r;
            Zr[h * 104 + c] = (_Float16)yr[r];
            Zi[h * 104 + c] = (_Float16)yi[r];
        }
    }
    __syncthreads();

    // vector store back (in-place)
    for (int i = tid; i < 384; i += 768) {
        int h = i / 12, cc = (i % 12) * 8;
        half8 vr = *(const half8*)&Zr[h * 104 + cc];
        half8 vi = *(const half8*)&Zi[h * 104 + cc];
        *(half8*)(Xr + base + (size_t)h * 768 + cc) = vr;
        *(half8*)(Xi + base + (size_t)h * 768 + cc) = vi;
    }
}

// ---------------- f32 -> f16 elementwise (vectorized x4) ----------------
__global__ __launch_bounds__(256) void cvt_f16(const float* __restrict__ in,
        _Float16* __restrict__ out)
{
    int i = blockIdx.x * 256 + threadIdx.x;
    float4 v = ((const float4*)in)[i];
    half4v o;
    o.x = (_Float16)v.x; o.y = (_Float16)v.y; o.z = (_Float16)v.z; o.w = (_Float16)v.w;
    ((half4v*)out)[i] = o;
}

// ---------------- f32 [K][N] -> f16 [N][K] transpose ----------------
__global__ __launch_bounds__(256) void cvt_transpose(const float* __restrict__ in,
        _Float16* __restrict__ out, int K, int N)
{
    __shared__ float tile[32][33];
    int kb = blockIdx.x * 32, nb = blockIdx.y * 32;
    int tx = threadIdx.x & 31, ty = threadIdx.x >> 5;
    #pragma unroll
    for (int r = 0; r < 32; r += 8)
        tile[ty + r][tx] = in[(size_t)(kb + ty + r) * N + nb + tx];
    __syncthreads();
    #pragma unroll
    for (int r = 0; r < 32; r += 8)
        out[(size_t)(nb + ty + r) * K + kb + tx] = (_Float16)tile[tx][ty + r];
}

// ---------------- R18: batched fc-weight transpose (8 matrices, 1 launch) ----------------
__global__ __launch_bounds__(256) void cvt_transpose8(const float* __restrict__ fc1w,
        const float* __restrict__ fc2w, _Float16* __restrict__ WtAll)
{
    __shared__ float tile[32][33];
    const int z  = blockIdx.y;
    const int l  = z & 1;
    const int d  = z >> 1;
    const int K  = l ? 3072 : 768;
    const int N  = l ? 768 : 3072;
    const float* src = (l ? fc2w : fc1w) + (size_t)d * 2359296;
    _Float16*    dst = WtAll + (size_t)z * 2359296;
    const int nt = N >> 5;
    int kb = (blockIdx.x / nt) * 32;
    int nb = (blockIdx.x % nt) * 32;
    int tx = threadIdx.x & 31, ty = threadIdx.x >> 5;
    #pragma unroll
    for (int r = 0; r < 32; r += 8)
        tile[ty + r][tx] = src[(size_t)(kb + ty + r) * N + nb + tx];
    __syncthreads();
    #pragma unroll
    for (int r = 0; r < 32; r += 8)
        dst[(size_t)(nb + ty + r) * K + kb + tx] = (_Float16)tile[tx][ty + r];
}

// ---------------- R19: fc1 deep-pipeline 128x192, 8 waves, 3 buffers, 1 barrier/tile ----------------
// M=4096, N=3072, K=768 fixed; grid (16,32) = 512 blocks, 1 blk/CU (120KB LDS).
// Per tile: loop-top {vmcnt(5), barrier} then 2 phases of {ds_read ks-half,
// issue part of stage(t+2) into buf (t+2)%3, 12 MFMA}. Two tiles in flight.
__global__ __launch_bounds__(512, 1) void fc1_deep(const _Float16* __restrict__ A,
        const _Float16* __restrict__ Bt, const float* __restrict__ bias,
        _Float16* __restrict__ C16)
{
    constexpr int K = 768, NT = 12, N = 3072;
    __shared__ _Float16 Al[3][128 * 64];   // 48 KB
    __shared__ _Float16 Bl[3][192 * 64];   // 72 KB

    const int tid  = threadIdx.x;
    const int wave = tid >> 6;            // 0..7
    const int lane = tid & 63;
    const int wr   = wave >> 2;           // 0..1 (M)
    const int wc   = wave & 3;            // 0..3 (N)
    const int lr   = lane & 15;
    const int quad = lane >> 4;

    // XCD swizzle (2D): gx=16, gy=32 -> cols=8, rows=8 per XCD patch
    const int gx = gridDim.x, gy = gridDim.y;
    int bx = blockIdx.x, by = blockIdx.y;
    {
        int id = by * gx + bx;
        int xcd = id & 7, j = id >> 3;
        int cols = gx >> 1;
        int rows = gy >> 2;
        int jr = j / cols, jc = j % cols;
        by = (xcd >> 1) * rows + jr;
        bx = (xcd & 1) * cols + jc;
    }
    const int row0 = by * 128;
    const int col0 = bx * 192;

    // staging (same XOR-swizzled pattern as gemm128d): per 64-row unit each
    // wave covers 8 rows; lane l: row=l>>3, phys chunk=l&7, src chunk=(l&7)^row.
    const int srow = lane >> 3;
    const int schk = (lane & 7) ^ (srow & 7);
    const _Float16* Ab = A  + (size_t)(row0 + wave * 8 + srow) * K + schk * 8;
    const _Float16* Bb = Bt + (size_t)(col0 + wave * 8 + srow) * K + schk * 8;

    auto stageA3 = [&](int b, int kt) {        // 2 A-units + first B-unit
        const int k0 = kt * 64;
        async16(Ab + k0,                       &Al[b][(wave * 8) * 64]);
        async16(Ab + (size_t)64 * K + k0,      &Al[b][(64 + wave * 8) * 64]);
        async16(Bb + k0,                       &Bl[b][(wave * 8) * 64]);
    };
    auto stageB2 = [&](int b, int kt) {        // remaining 2 B-units
        const int k0 = kt * 64;
        async16(Bb + (size_t)64 * K + k0,      &Bl[b][(64 + wave * 8) * 64]);
        async16(Bb + (size_t)128 * K + k0,     &Bl[b][(128 + wave * 8) * 64]);
    };

    float4v acc[4][3];
    #pragma unroll
    for (int m = 0; m < 4; ++m)
        #pragma unroll
        for (int n = 0; n < 3; ++n) {
            float4v z = {0.f, 0.f, 0.f, 0.f};
            acc[m][n] = z;
        }

    // prologue: tiles 0 and 1 fully staged
    stageA3(0, 0); stageB2(0, 0);
    stageA3(1, 1); stageB2(1, 1);

    int cur = 0;
    for (int t = 0; t < NT; ++t) {
        if (t + 1 < NT) asm volatile("s_waitcnt vmcnt(5)" ::: "memory");
        else            asm volatile("s_waitcnt vmcnt(0)" ::: "memory");
        __builtin_amdgcn_s_barrier();     // tile-t data visible; buf (t+2)%3 free
        int nxt = cur + 2; if (nxt >= 3) nxt -= 3;
        #pragma unroll
        for (int ks = 0; ks < 2; ++ks) {
            const int cA = ((ks * 4 + quad) ^ (lr & 7)) * 8;
            half8 bf[3];
            #pragma unroll
            for (int n = 0; n < 3; ++n)
                bf[n] = *(const half8*)&Bl[cur][(wc * 48 + n * 16 + lr) * 64 + cA];
            half8 af[4];
            #pragma unroll
            for (int m = 0; m < 4; ++m)
                af[m] = *(const half8*)&Al[cur][(wr * 64 + m * 16 + lr) * 64 + cA];
            if (t + 2 < NT) {
                if (ks == 0) stageA3(nxt, t + 2);
                else         stageB2(nxt, t + 2);
            }
            __builtin_amdgcn_s_setprio(1);
            #pragma unroll
            for (int m = 0; m < 4; ++m)
                #pragma unroll
                for (int n = 0; n < 3; ++n)
                    acc[m][n] = __builtin_amdgcn_mfma_f32_16x16x32_f16(af[m], bf[n], acc[m][n], 0, 0, 0);
            __builtin_amdgcn_s_setprio(0);
        }
        ++cur; if (cur >= 3) cur -= 3;
    }

    // epilogue: bias + GELU -> f16 store
    #pragma unroll
    for (int n = 0; n < 3; ++n) {
        int col = col0 + wc * 48 + n * 16 + lr;
        float bj = bias[col];
        #pragma unroll
        for (int m = 0; m < 4; ++m) {
            int row = row0 + wr * 64 + m * 16 + quad * 4;
            #pragma unroll
            for (int r = 0; r < 4; ++r) {
                float v = acc[m][n][r] + bj;
                v = gelu_f(v);
                C16[(size_t)(row + r) * N + col] = (_Float16)v;
            }
        }
    }
}

// ---------------- R12/R18: 128-row-tile 8-wave GEMM, counted vmcnt (conv/head1) ----------------
// BN=64: WN=16 FN=1 BU=1 LPT=3. POS: add pos_emb in epilogue (conv).
template<int BN, int ACT, int POS>
__global__ __launch_bounds__(512, 4) void gemm128d(const _Float16* __restrict__ A,
        const _Float16* __restrict__ Bt, const float* __restrict__ bias,
        const float* __restrict__ pos, _Float16* __restrict__ C16,
        int M, int N, int K)
{
    constexpr int WN  = BN / 4;
    constexpr int FN  = WN / 16;
    constexpr int AU  = 2;                // A: 2 x 64-row units
    constexpr int BU  = BN / 64;
    constexpr int LPT = AU + BU;          // loads/thread/K-tile
    __shared__ _Float16 Al[2][128 * 64];
    __shared__ _Float16 Bl[2][BN * 64];

    const int tid  = threadIdx.x;
    const int wave = tid >> 6;            // 0..7
    const int lane = tid & 63;
    const int wr   = wave >> 2;           // 0..1 (M)
    const int wc   = wave & 3;            // 0..3 (N)
    const int lr   = lane & 15;
    const int quad = lane >> 4;

    // XCD swizzle (2D): per-XCD contiguous patch for L2 reuse
    const int gx = gridDim.x, gy = gridDim.y, nbk = gx * gy;
    int bx = blockIdx.x, by = blockIdx.y;
    if (!(gy & 3) && !(gx & 1)) {
        int id = by * gx + bx;
        int xcd = id & 7, j = id >> 3;
        int cols = gx >> 1;
        int rows = gy >> 2;
        int jr = j / cols, jc = j % cols;
        by = (xcd >> 1) * rows + jr;
        bx = (xcd & 1) * cols + jc;
    } else if (!(nbk & 7)) {
        int id  = by * gx + bx;
        int id2 = (id & 7) * (nbk >> 3) + (id >> 3);
        by = id2 / gx; bx = id2 % gx;
    }
    const int row0 = by * 128;
    const int col0 = bx * BN;

    // staging: per 64-row unit (64x64 halfs = 8KB) each wave covers 8 rows.
    const int srow = lane >> 3;
    const int schk = (lane & 7) ^ (srow & 7);
    const _Float16* Ab = A  + (size_t)(row0 + wave * 8 + srow) * K + schk * 8;
    const _Float16* Bb = Bt + (size_t)(col0 + wave * 8 + srow) * K + schk * 8;

    auto stage = [&](int b, int kt) {
        const int k0 = kt * 64;
        #pragma unroll
        for (int u = 0; u < AU; ++u)
            async16(Ab + (size_t)u * 64 * K + k0, &Al[b][(u * 64 + wave * 8) * 64]);
        #pragma unroll
        for (int u = 0; u < BU; ++u)
            async16(Bb + (size_t)u * 64 * K + k0, &Bl[b][(u * 64 + wave * 8) * 64]);
    };

    float4v acc[4][FN];
    #pragma unroll
    for (int m = 0; m < 4; ++m)
        #pragma unroll
        for (int n = 0; n < FN; ++n) {
            float4v z = {0.f, 0.f, 0.f, 0.f};
            acc[m][n] = z;
        }

    auto compute = [&](int cb) {
        #pragma unroll
        for (int ks = 0; ks < 2; ++ks) {
            const int cA = ((ks * 4 + quad) ^ (lr & 7)) * 8;   // swizzled chunk (halfs)
            half8 bf[FN];
            #pragma unroll
            for (int n = 0; n < FN; ++n)
                bf[n] = *(const half8*)&Bl[cb][(wc * WN + n * 16 + lr) * 64 + cA];
            half8 af[4];
            #pragma unroll
            for (int m = 0; m < 4; ++m)
                af[m] = *(const half8*)&Al[cb][(wr * 64 + m * 16 + lr) * 64 + cA];
            __builtin_amdgcn_s_setprio(1);
            #pragma unroll
            for (int m = 0; m < 4; ++m)
                #pragma unroll
                for (int n = 0; n < FN; ++n)
                    acc[m][n] = __builtin_amdgcn_mfma_f32_16x16x32_f16(af[m], bf[n], acc[m][n], 0, 0, 0);
            __builtin_amdgcn_s_setprio(0);
        }
    };

    const int NT = K >> 6;                // K=768 -> 12 tiles
    stage(0, 0);
    stage(1, 1);
    for (int t = 0; t < NT; ++t) {
        if (t + 1 < NT) {
            if constexpr (LPT == 5) asm volatile("s_waitcnt vmcnt(5)" ::: "memory");
            else                    asm volatile("s_waitcnt vmcnt(3)" ::: "memory");
        } else {
            asm volatile("s_waitcnt vmcnt(0)" ::: "memory");
        }
        __builtin_amdgcn_s_barrier();     // all waves' tile-t loads visible
        compute(t & 1);
        __builtin_amdgcn_s_barrier();     // all waves done reading buf[t&1]
        if (t + 2 < NT) stage(t & 1, t + 2);   // prefetch into just-freed buffer
    }

    // epilogue: bias (+pos) (+GELU) -> f16 store
    #pragma unroll
    for (int n = 0; n < FN; ++n) {
        int col = col0 + wc * WN + n * 16 + lr;
        float bj = bias[col];
        #pragma unroll
        for (int m = 0; m < 4; ++m) {
            int row = row0 + wr * 64 + m * 16 + quad * 4;
            #pragma unroll
            for (int r = 0; r < 4; ++r) {
                float v = acc[m][n][r] + bj;
                if (POS) v += pos[(size_t)((row + r) & 1023) * N + col];
                if (ACT) v = gelu_f(v);
                C16[(size_t)(row + r) * N + col] = (_Float16)v;
            }
        }
    }
}

// ---------------- R17: fc2 + fused forward W-DFT, 64x64 tile, 4 waves, 3 blk/CU ----------------
__global__ __launch_bounds__(256, 3) void fc2_fused(const _Float16* __restrict__ A,
        const _Float16* __restrict__ Bt, const float* __restrict__ bias,
        _Float16* __restrict__ C16, _Float16* __restrict__ XR,
        _Float16* __restrict__ XI)
{
    constexpr int K = 3072;
    constexpr int NT = 48;
    __shared__ _Float16 Al[2][64 * 64];        // 16 KB
    __shared__ _Float16 Bl[2][64 * 64];        // 16 KB
    __shared__ alignas(16) _Float16 Tl[2 * 64 * 40];           // 10 KB  [h][c][w pad40]
    __shared__ alignas(16) _Float16 ECl[1024], ESl[1024];      // 4 KB

    const int tid  = threadIdx.x;
    const int wave = tid >> 6;            // 0..3
    const int lane = tid & 63;
    const int wr   = wave >> 1;           // 0..1 (M: 32-row half)
    const int wc   = wave & 1;            // 0..1 (N: 32-col half)
    const int lr   = lane & 15;
    const int quad = lane >> 4;

    // twiddle fill early (hides under prologue load latency)
    for (int i = tid; i < 1024; i += 256) {
        int kw = i >> 5, w = i & 31;
        float a = ((kw * w) & 31) * STEP32;
        ECl[i] = (_Float16)(cosf(a) * 0.03125f);
        ESl[i] = (_Float16)(-sinf(a) * 0.03125f);
    }

    // XCD swizzle (2D): gx=12, gy=64 -> cols=6, rows=16 per XCD patch
    const int gx = gridDim.x, gy = gridDim.y;
    int bx = blockIdx.x, by = blockIdx.y;
    {
        int id = by * gx + bx;
        int xcd = id & 7, j = id >> 3;
        int cols = gx >> 1;
        int rows = gy >> 2;
        int jr = j / cols, jc = j % cols;
        by = (xcd >> 1) * rows + jr;
        bx = (xcd & 1) * cols + jc;
    }
    const int row0 = by * 64;
    const int col0 = bx * 64;

    // staging: A/B each 2 units of 32 rows; wave covers 8 rows/unit.
    const int srow = lane >> 3;
    const int schk = (lane & 7) ^ srow;
    const _Float16* Ab = A  + (size_t)(row0 + wave * 8 + srow) * K + schk * 8;
    const _Float16* Bb = Bt + (size_t)(col0 + wave * 8 + srow) * K + schk * 8;

    auto stage = [&](int b, int kt) {
        const int k0 = kt * 64;
        #pragma unroll
        for (int u = 0; u < 2; ++u)
            async16(Ab + (size_t)u * 32 * K + k0, &Al[b][(u * 32 + wave * 8) * 64]);
        #pragma unroll
        for (int u = 0; u < 2; ++u)
            async16(Bb + (size_t)u * 32 * K + k0, &Bl[b][(u * 32 + wave * 8) * 64]);
    };

    float4v acc[2][2];
    #pragma unroll
    for (int m = 0; m < 2; ++m)
        #pragma unroll
        for (int n = 0; n < 2; ++n) {
            float4v z = {0.f, 0.f, 0.f, 0.f};
            acc[m][n] = z;
        }

    auto compute = [&](int cb) {
        #pragma unroll
        for (int ks = 0; ks < 2; ++ks) {
            const int cA = ((ks * 4 + quad) ^ (lr & 7)) * 8;   // swizzled chunk (halfs)
            half8 bf[2], af[2];
            #pragma unroll
            for (int n = 0; n < 2; ++n)
                bf[n] = *(const half8*)&Bl[cb][(wc * 32 + n * 16 + lr) * 64 + cA];
            #pragma unroll
            for (int m = 0; m < 2; ++m)
                af[m] = *(const half8*)&Al[cb][(wr * 32 + m * 16 + lr) * 64 + cA];
            __builtin_amdgcn_s_setprio(1);
            #pragma unroll
            for (int m = 0; m < 2; ++m)
                #pragma unroll
                for (int n = 0; n < 2; ++n)
                    acc[m][n] = __builtin_amdgcn_mfma_f32_16x16x32_f16(af[m], bf[n], acc[m][n], 0, 0, 0);
            __builtin_amdgcn_s_setprio(0);
        }
    };

    stage(0, 0);
    stage(1, 1);
    for (int t = 0; t < NT; ++t) {
        if (t + 1 < NT) asm volatile("s_waitcnt vmcnt(4)" ::: "memory");
        else            asm volatile("s_waitcnt vmcnt(0)" ::: "memory");
        __builtin_amdgcn_s_barrier();
        compute(t & 1);
        __builtin_amdgcn_s_barrier();
        if (t + 2 < NT) stage(t & 1, t + 2);
    }

    // epilogue: bias -> t_h write + Tl staging ([h][c][w] pad40)
    #pragma unroll
    for (int n = 0; n < 2; ++n) {
        int cc  = wc * 32 + n * 16 + lr;
        int col = col0 + cc;
        float bj = bias[col];
        #pragma unroll
        for (int m = 0; m < 2; ++m) {
            int row = row0 + wr * 32 + m * 16 + quad * 4;
            #pragma unroll
            for (int r = 0; r < 4; ++r) {
                float v = acc[m][n][r] + bj;
                C16[(size_t)(row + r) * 768 + col] = (_Float16)v;
                int lrow = row + r - row0;
                Tl[((lrow >> 5) * 64 + cc) * 40 + (lrow & 31)] = (_Float16)v;
            }
        }
    }
    __syncthreads();

    // per-wave h-row DFT: wave handles h = wave>>1, cols (wave&1)*32..+31
    const int h     = wave >> 1;
    const int cbase = (wave & 1) * 32;
    const int b     = row0 >> 10;
    const int hp    = ((row0 >> 5) & 31) + h;
    half8 eC0 = *(const half8*)&ECl[lr * 32 + quad * 8];
    half8 eC1 = *(const half8*)&ECl[(16 + lr) * 32 + quad * 8];
    half8 eS0 = *(const half8*)&ESl[lr * 32 + quad * 8];
    half8 eS1 = *(const half8*)&ESl[(16 + lr) * 32 + quad * 8];
    float4v xr[2][2], xi[2][2];
    #pragma unroll
    for (int m = 0; m < 2; ++m)
        #pragma unroll
        for (int nj = 0; nj < 2; ++nj) {
            float4v z = {0.f, 0.f, 0.f, 0.f};
            xr[m][nj] = z; xi[m][nj] = z;
        }
    #pragma unroll
    for (int nj = 0; nj < 2; ++nj) {
        half8 tb = *(const half8*)&Tl[(h * 64 + cbase + nj * 16 + lr) * 40 + quad * 8];
        xr[0][nj] = __builtin_amdgcn_mfma_f32_16x16x32_f16(eC0, tb, xr[0][nj], 0, 0, 0);
        xr[1][nj] = __builtin_amdgcn_mfma_f32_16x16x32_f16(eC1, tb, xr[1][nj], 0, 0, 0);
        xi[0][nj] = __builtin_amdgcn_mfma_f32_16x16x32_f16(eS0, tb, xi[0][nj], 0, 0, 0);
        xi[1][nj] = __builtin_amdgcn_mfma_f32_16x16x32_f16(eS1, tb, xi[1][nj], 0, 0, 0);
    }
    #pragma unroll
    for (int m = 0; m < 2; ++m)
        #pragma unroll
        for (int r = 0; r < 4; ++r) {
            int kw = m * 16 + quad * 4 + r;
            if (kw < 17) {
                #pragma unroll
                for (int nj = 0; nj < 2; ++nj) {
                    int c = col0 + cbase + nj * 16 + lr;
                    size_t g = ((size_t)(b * 17 + kw) * 32 + hp) * 768 + c;
                    XR[g] = (_Float16)xr[m][nj][r];
                    XI[g] = (_Float16)xi[m][nj][r];
                }
            }
        }
}

// ---------------- R14: head2 64x64 tile, 4 waves, counted-vmcnt, scatter out ----------------
__global__ __launch_bounds__(256, 4) void head2_k(const _Float16* __restrict__ A,
        const _Float16* __restrict__ Bt, const float* __restrict__ bias,
        float* __restrict__ C32, int f_idx)
{
    constexpr int K = 1536;
    constexpr int NT = 24;
    __shared__ _Float16 Al[2][64 * 64];   // 16 KB
    __shared__ _Float16 Bl[2][64 * 64];   // 16 KB

    const int tid  = threadIdx.x;
    const int wave = tid >> 6;            // 0..3
    const int lane = tid & 63;
    const int wr   = wave >> 1;
    const int wc   = wave & 1;
    const int lr   = lane & 15;
    const int quad = lane >> 4;

    const int row0 = blockIdx.x * 64;

    const int srow = lane >> 3;
    const int schk = (lane & 7) ^ srow;
    const _Float16* Ab = A  + (size_t)(row0 + wave * 8 + srow) * K + schk * 8;
    const _Float16* Bb = Bt + (size_t)(wave * 8 + srow) * K + schk * 8;

    auto stage = [&](int b, int kt) {
        const int k0 = kt * 64;
        #pragma unroll
        for (int u = 0; u < 2; ++u)
            async16(Ab + (size_t)u * 32 * K + k0, &Al[b][(u * 32 + wave * 8) * 64]);
        #pragma unroll
        for (int u = 0; u < 2; ++u)
            async16(Bb + (size_t)u * 32 * K + k0, &Bl[b][(u * 32 + wave * 8) * 64]);
    };

    float4v acc[2][2];
    #pragma unroll
    for (int m = 0; m < 2; ++m)
        #pragma unroll
        for (int n = 0; n < 2; ++n) {
            float4v z = {0.f, 0.f, 0.f, 0.f};
            acc[m][n] = z;
        }

    auto compute = [&](int cb) {
        #pragma unroll
        for (int ks = 0; ks < 2; ++ks) {
            const int cA = ((ks * 4 + quad) ^ (lr & 7)) * 8;
            half8 bf[2], af[2];
            #pragma unroll
            for (int n = 0; n < 2; ++n)
                bf[n] = *(const half8*)&Bl[cb][(wc * 32 + n * 16 + lr) * 64 + cA];
            #pragma unroll
            for (int m = 0; m < 2; ++m)
                af[m] = *(const half8*)&Al[cb][(wr * 32 + m * 16 + lr) * 64 + cA];
            #pragma unroll
            for (int m = 0; m < 2; ++m)
                #pragma unroll
                for (int n = 0; n < 2; ++n)
                    acc[m][n] = __builtin_amdgcn_mfma_f32_16x16x32_f16(af[m], bf[n], acc[m][n], 0, 0, 0);
        }
    };

    stage(0, 0);
    stage(1, 1);
    for (int t = 0; t < NT; ++t) {
        if (t + 1 < NT) asm volatile("s_waitcnt vmcnt(4)" ::: "memory");
        else            asm volatile("s_waitcnt vmcnt(0)" ::: "memory");
        __builtin_amdgcn_s_barrier();
        compute(t & 1);
        __builtin_amdgcn_s_barrier();
        if (t + 2 < NT) stage(t & 1, t + 2);
    }

    // scatter epilogue: out[b][h][w][f] pixel-shuffle
    #pragma unroll
    for (int n = 0; n < 2; ++n) {
        int col = wc * 32 + n * 16 + lr;
        float bj = bias[col];
        int p = col >> 3, q = col & 7;
        #pragma unroll
        for (int m = 0; m < 2; ++m) {
            int row = row0 + wr * 32 + m * 16 + quad * 4;
            #pragma unroll
            for (int r = 0; r < 4; ++r) {
                float v = acc[m][n][r] + bj;
                int rowv = row + r;
                int bq = rowv >> 10, hp = (rowv >> 5) & 31, wp = rowv & 31;
                C32[(((size_t)(bq * 256 + hp * 8 + p)) * 256 + wp * 8 + q) * 4 + f_idx] = v;
            }
        }
    }
}

// ---------------- fp16 MFMA GEMM, depth-3 counted-vmcnt pipeline (fallback fc2 only) ----------------
template<int BN, int OUT_MODE, int ACT>
__global__ __launch_bounds__(256) void gemm_h(const _Float16* __restrict__ A,
        const _Float16* __restrict__ Bt, const float* __restrict__ bias,
        const float* __restrict__ pos, float* __restrict__ C32,
        _Float16* __restrict__ C16, _Float16* __restrict__ XR,
        _Float16* __restrict__ XI, int M, int N, int K, int f_idx)
{
    constexpr int WN  = BN / 2;
    constexpr int FN  = WN / 16;
    constexpr int NBJ = BN / 64;
    constexpr int LPT = 2 + NBJ;          // vmem loads per thread per K-tile
    __shared__ _Float16 Al[4][128 * 32];
    __shared__ _Float16 Bl[4][BN * 32];

    const int tid  = threadIdx.x;
    const int wave = tid >> 6;
    const int lane = tid & 63;
    const int wr   = wave >> 1;
    const int wc   = wave & 1;
    const int lr   = lane & 15;
    const int quad = lane >> 4;

    const int gx = gridDim.x, gy = gridDim.y, nbk = gx * gy;
    int bx = blockIdx.x, by = blockIdx.y;
    if (!(gy & 3) && !(gx & 1)) {
        int id = by * gx + bx;
        int xcd = id & 7, j = id >> 3;
        int cols = gx >> 1;
        int rows = gy >> 2;
        int jr = j / cols, jc = j % cols;
        by = (xcd >> 1) * rows + jr;
        bx = (xcd & 1) * cols + jc;
    } else if (!(nbk & 7)) {
        int id  = by * gx + bx;
        int id2 = (id & 7) * (nbk >> 3) + (id >> 3);
        by = id2 / gx; bx = id2 % gx;
    }
    const int row0 = by * 128;
    const int col0 = bx * BN;

    const int srow = lane >> 2;
    const int skof = ((lane & 3) ^ (srow & 3)) * 8;

    auto stage = [&](int b, int kt) {
        const int k0 = kt << 5;
        #pragma unroll
        for (int j = 0; j < 2; ++j)
            async16(A + (size_t)(row0 + j * 64 + wave * 16 + srow) * K + k0 + skof,
                    &Al[b][(j * 64 + wave * 16) * 32]);
        #pragma unroll
        for (int j = 0; j < NBJ; ++j)
            async16(Bt + (size_t)(col0 + j * 64 + wave * 16 + srow) * K + k0 + skof,
                    &Bl[b][(j * 64 + wave * 16) * 32]);
    };

    float4v acc[4][FN];
    #pragma unroll
    for (int i = 0; i < 4; ++i)
        #pragma unroll
        for (int j = 0; j < FN; ++j) {
            float4v z = {0.f, 0.f, 0.f, 0.f};
            acc[i][j] = z;
        }

    auto compute = [&](int cb) {
        const int cA = (quad ^ (lr & 3)) * 8;   // swizzled chunk (halfs)
        half8 af[4], bf[FN];
        #pragma unroll
        for (int i = 0; i < 4; ++i)
            af[i] = *(const half8*)&Al[cb][(wr * 64 + i * 16 + lr) * 32 + cA];
        #pragma unroll
        for (int j = 0; j < FN; ++j)
            bf[j] = *(const half8*)&Bl[cb][(wc * WN + j * 16 + lr) * 32 + cA];
        #pragma unroll
        for (int i = 0; i < 4; ++i)
            #pragma unroll
            for (int j = 0; j < FN; ++j)
                acc[i][j] = __builtin_amdgcn_mfma_f32_16x16x32_f16(af[i], bf[j], acc[i][j], 0, 0, 0);
    };

    const int KT = K >> 5;
    stage(0, 0); stage(1, 1); stage(2, 2);
    int kt = 0;
    for (; kt < KT - 3; ++kt) {
        stage((kt + 3) & 3, kt + 3);
        if constexpr (LPT == 4) asm volatile("s_waitcnt vmcnt(12)" ::: "memory");
        else                    asm volatile("s_waitcnt vmcnt(9)"  ::: "memory");
        __builtin_amdgcn_s_barrier();
        compute(kt & 3);
        asm volatile("" ::: "memory");
        __builtin_amdgcn_s_barrier();
    }
    if constexpr (LPT == 4) asm volatile("s_waitcnt vmcnt(8)" ::: "memory");
    else                    asm volatile("s_waitcnt vmcnt(6)" ::: "memory");
    __builtin_amdgcn_s_barrier();
    compute(kt & 3); ++kt;
    asm volatile("" ::: "memory");
    __builtin_amdgcn_s_barrier();
    if constexpr (LPT == 4) asm volatile("s_waitcnt vmcnt(4)" ::: "memory");
    else                    asm volatile("s_waitcnt vmcnt(3)" ::: "memory");
    __builtin_amdgcn_s_barrier();
    compute(kt & 3); ++kt;
    asm volatile("" ::: "memory");
    __builtin_amdgcn_s_barrier();
    asm volatile("s_waitcnt vmcnt(0)" ::: "memory");
    __builtin_amdgcn_s_barrier();
    compute(kt & 3);

    #pragma unroll
    for (int j = 0; j < FN; ++j) {
        int col = col0 + wc * WN + j * 16 + lr;
        float bj = bias[col];
        #pragma unroll
        for (int i = 0; i < 4; ++i) {
            int row = row0 + wr * 64 + i * 16 + quad * 4;
            #pragma unroll
            for (int r = 0; r < 4; ++r) {
                float v = acc[i][j][r] + bj;
                if (pos) v += pos[(size_t)((row + r) & 1023) * N + col];
                if (ACT) v = gelu_f(v);
                if (OUT_MODE == 3) {
                    int rowv = row + r;
                    int bq = rowv >> 10, hp = (rowv >> 5) & 31, wp = rowv & 31;
                    int p = col >> 3, q = col & 7;
                    C32[(((size_t)(bq * 256 + hp * 8 + p)) * 256 + wp * 8 + q) * 4 + f_idx] = v;
                } else {
                    C16[(size_t)(row + r) * N + col] = (_Float16)v;
                }
            }
        }
    }
}

// ---------------- launch ----------------
extern "C" void kernel_launch(void* const* d_in, const int* in_sizes, int n_in,
                              void* d_out, int out_size, void* d_ws, size_t ws_size,
                              hipStream_t stream) {
    const float* x        = (const float*)d_in[0];
    const float* grd      = (const float*)d_in[1];
    const float* conv_w   = (const float*)d_in[2];
    const float* conv_b   = (const float*)d_in[3];
    const float* pos_emb  = (const float*)d_in[4];
    const float* w1       = (const float*)d_in[5];
    const float* b1       = (const float*)d_in[6];
    const float* w2       = (const float*)d_in[7];
    const float* b2       = (const float*)d_in[8];
    const float* fc1_w    = (const float*)d_in[9];
    const float* fc1_b    = (const float*)d_in[10];
    const float* fc2_w    = (const float*)d_in[11];
    const float* fc2_b    = (const float*)d_in[12];
    const float* head_w1  = (const float*)d_in[13];
    const float* head_b1  = (const float*)d_in[14];
    const float* head_w2  = (const float*)d_in[15];
    const float* head_b2  = (const float*)d_in[16];
    float* out = (float*)d_out;
    float* ws  = (float*)d_ws;

    // ---- workspace layout, sizes in float units ----
    float* pf = ws;
    _Float16* t_h     = (_Float16*)pf; pf += 1572864;   // 4096x768 f16 (residual state)
    _Float16* Wsp     = (_Float16*)pf; pf += 589824;    // 128x9216 f16 spectral weights
    _Float16* h1t     = (_Float16*)pf; pf += 589824;    // [1536][768] f16
    _Float16* h2t     = (_Float16*)pf; pf += 49152;     // [64][1536] f16
    _Float16* convw_h = (_Float16*)pf; pf += 294912;    // 768x768 f16 (prepass only)
    float* alias    = pf;              pf += 6291456;   // hid_h 4096x3072 f16
    _Float16* hid_h = (_Float16*)alias;
    _Float16* WtAll = (_Float16*)pf;   pf += 9437184;   // 8 x [N][K] fc weights f16
    // fallback xa inside alias (hid dead when xa live); full mode: dedicated xa after WtAll
    _Float16* xa_r_fb = (_Float16*)alias;
    _Float16* xa_i_fb = (_Float16*)(alias + 835584);
    _Float16* xa_r_fu = (_Float16*)pf;                  // +835,584 f
    _Float16* xa_i_fu = (_Float16*)(pf + 835584);       // +835,584 f
    size_t full_total = (size_t)(pf - ws) + 1671168;    // 20,496,384 f = 82.0 MB
    bool full = ws_size >= full_total * 4ull;
    _Float16* xa_r = full ? xa_r_fu : xa_r_fb;
    _Float16* xa_i = full ? xa_i_fu : xa_i_fb;
    _Float16* A_h  = (_Float16*)alias;                  // prepass-only (gather input, dead after)

    // ---- prepass ----
    prep_specw<<<dim3(128), 256, 0, stream>>>(w1, w2, Wsp);
    cvt_f16<<<dim3(576), 256, 0, stream>>>(conv_w, convw_h);
    cvt_transpose<<<dim3(24, 48), 256, 0, stream>>>(head_w1, h1t, 768, 1536);
    cvt_transpose<<<dim3(48, 2), 256, 0, stream>>>(head_w2, h2t, 1536, 64);
    cvt_transpose8<<<dim3(2304, 8), 256, 0, stream>>>(fc1_w, fc2_w, WtAll);
    gather_patch<<<dim3(12288), 256, 0, stream>>>(x, grd, A_h);
    gemm128d<64, 0, 1><<<dim3(12, 32), 512, 0, stream>>>(
        A_h, convw_h, conv_b, pos_emb, t_h, 4096, 768, 768);
    dft_fwd_w<<<dim3(128, 3), 256, 0, stream>>>(t_h, xa_r, xa_i);

    for (int f = 0; f < 4; ++f) {
        for (int d = 0; d < 4; ++d) {
            // fused H-DFT + complex MLP + H-IDFT (in-place on xa), 12 waves
            spec_fused<<<dim3(68, 8), 768, 0, stream>>>(
                xa_r, xa_i,
                Wsp + (size_t)(d * 4 + 0) * 73728, Wsp + (size_t)(d * 4 + 1) * 73728,
                Wsp + (size_t)(d * 4 + 2) * 73728, Wsp + (size_t)(d * 4 + 3) * 73728,
                b1 + d * 1536, b1 + d * 1536 + 768,
                b2 + d * 1536, b2 + d * 1536 + 768);
            // irfft2 W-pass + f16 residual (in place on t_h) -- MFMA version (R15)
            idft_w_mfma<<<dim3(128, 4), 256, 0, stream>>>(xa_r, xa_i, t_h);
            // channel MLP fc1: deep-pipeline 128x192, 3 buffers, 1 barrier/tile
            fc1_deep<<<dim3(16, 32), 512, 0, stream>>>(
                t_h, WtAll + (size_t)(2 * d) * 2359296, fc1_b + d * 3072, hid_h);
            if (full) {
                // fc2 + fused forward W-DFT (seeds xa for the next spectral block)
                fc2_fused<<<dim3(12, 64), 256, 0, stream>>>(
                    hid_h, WtAll + (size_t)(2 * d + 1) * 2359296, fc2_b + d * 768,
                    t_h, xa_r, xa_i);
            } else {
                gemm_h<64, 1, 0><<<dim3(12, 32), 256, 0, stream>>>(
                    hid_h, WtAll + (size_t)(2 * d + 1) * 2359296, fc2_b + d * 768,
                    nullptr, nullptr, t_h, nullptr, nullptr, 4096, 768, 3072, 0);
                dft_fwd_w<<<dim3(128, 3), 256, 0, stream>>>(t_h, xa_r, xa_i);
            }
        }
        // head on current state (t_h from fc2): 64-col tile, 768 blocks = 3/CU
        gemm128d<64, 1, 0><<<dim3(24, 32), 512, 0, stream>>>(
            t_h, h1t, head_b1, nullptr, hid_h, 4096, 1536, 768);
        head2_k<<<dim3(64), 256, 0, stream>>>(
            hid_h, h2t, head_b2, out, f);
    }
}